// Round 2
// baseline (228.745 us; speedup 1.0000x reference)
//
#include <hip/hip_runtime.h>

// NCC loss, fully fused: products + separable 9^3 box sums + cc + mean, one pass.
// Input vols: [B=2][D=160][H=192][W=160] fp32. Output: scalar fp32 = -mean(cc).
// R2: DC 40->20 (grid z 8->16, 1920 blocks) to lift occupancy 3.75 -> ~7 blocks/CU
// (LDS residency cap at 21 KB/block). Costs 1.4x vs 1.2x d-halo staging redundancy.

#define B_   2
#define D_   160
#define H_   192
#define W_   160
#define TH   16            // output tile h
#define TW   16            // output tile w
#define SH   24            // TH + 8 halo
#define SW   24            // TW + 8 halo
#define SSTR 37            // stage row stride (floats), padded for bank spread
#define WSTR 17            // wsum/hsum row stride
#define DC   20            // d outputs per chunk (160/20 = 8 chunks)
#define NCHUNK (D_/DC)
#define NSTEP (DC + 8)     // slices streamed per chunk
#define WIN3_INV (1.0f/729.0f)
#define NTOT 9830400.0f    // 2*160*192*160

__global__ __launch_bounds__(256) void ncc_fused(
    const float* __restrict__ I, const float* __restrict__ J,
    float* __restrict__ out)
{
  const int tid  = threadIdx.x;
  const int w0   = blockIdx.x * TW;
  const int h0   = blockIdx.y * TH;
  const int bz   = blockIdx.z;
  const int bb   = bz >> 3;                 // batch (8 chunks per batch)
  const int d_lo = (bz & (NCHUNK-1)) * DC;  // chunk start

  __shared__ float sI[SH*SSTR];
  __shared__ float sJ[SH*SSTR];
  __shared__ float wsum[5*SH*WSTR];    // w-summed, rows = h-halo (24), cols = 16
  __shared__ float hsum[5*TH*WSTR];    // w+h summed, 16x16 per field
  __shared__ float red[4];

  // per-output-column d-window state: 9-deep ring + running sums, 5 fields
  float ring[5][9];
  float S[5];
  #pragma unroll
  for (int f = 0; f < 5; ++f) {
    S[f] = 0.f;
    #pragma unroll
    for (int k = 0; k < 9; ++k) ring[f][k] = 0.f;
  }
  float acc = 0.f;

  // stage-role indices
  const int wr  = tid >> 3;    // w-stage: row 0..23 (tid<192)
  const int wp  = tid & 7;     // w-stage: output pair 0..7
  const int hwi = tid & 15;    // h-stage: w index
  const int hf  = (tid >> 4) % 5;   // h-stage: field
  const int hph = tid / 80;    // h-stage: half 0/1 (tid<160)
  const int rw  = tid & 15;    // ring stage: w
  const int rh  = tid >> 4;    // ring stage: h

  for (int step = 0; step < NSTEP; ++step) {
    const int s = d_lo - 4 + step;
    const bool sin_d = (unsigned)s < (unsigned)D_;
    const size_t slice_base = (size_t)(bb*D_ + s)*H_;

    // ---- stage raw I,J slice tile into LDS (zero OOB = 'same' zero pad) ----
    for (int i = tid; i < SH*SW; i += 256) {
      const int r = i / SW, c = i - r*SW;
      const int gh = h0 - 4 + r, gw = w0 - 4 + c;
      float vi = 0.f, vj = 0.f;
      if (sin_d && (unsigned)gh < (unsigned)H_ && (unsigned)gw < (unsigned)W_) {
        const size_t off = (slice_base + gh)*W_ + gw;
        vi = I[off]; vj = J[off];
      }
      sI[r*SSTR + c] = vi;
      sJ[r*SSTR + c] = vj;
    }
    __syncthreads();

    // ---- w-window sums (run of 2 outputs/thread, 5 fields on the fly) ----
    if (tid < 192) {
      float s0[5] = {0,0,0,0,0}, s1[5] = {0,0,0,0,0};
      const int base = wr*SSTR + 2*wp;
      #pragma unroll
      for (int k = 0; k < 10; ++k) {
        const float iv = sI[base + k];
        const float jv = sJ[base + k];
        const float p2 = iv*iv, p3 = jv*jv, p4 = iv*jv;
        if (k < 9) { s0[0]+=iv; s0[1]+=jv; s0[2]+=p2; s0[3]+=p3; s0[4]+=p4; }
        if (k > 0) { s1[0]+=iv; s1[1]+=jv; s1[2]+=p2; s1[3]+=p3; s1[4]+=p4; }
      }
      const int ob = wr*WSTR + 2*wp;
      #pragma unroll
      for (int f = 0; f < 5; ++f) {
        wsum[f*(SH*WSTR) + ob]     = s0[f];
        wsum[f*(SH*WSTR) + ob + 1] = s1[f];
      }
    }
    __syncthreads();

    // ---- h-window sums (run of 8 outputs/thread, one field each) ----
    if (tid < 160) {
      float v[16];
      const int fb = hf*(SH*WSTR) + hwi;
      #pragma unroll
      for (int k = 0; k < 16; ++k) v[k] = wsum[fb + (8*hph + k)*WSTR];
      float sum = 0.f;
      #pragma unroll
      for (int k = 0; k < 9; ++k) sum += v[k];
      const int hb = hf*(TH*WSTR) + hwi;
      hsum[hb + (8*hph)*WSTR] = sum;
      #pragma unroll
      for (int k = 1; k < 8; ++k) {
        sum += v[k+8] - v[k-1];
        hsum[hb + (8*hph + k)*WSTR] = sum;
      }
    }
    __syncthreads();

    // ---- d ring update + cc (every thread owns one (h,w) column) ----
    {
      float nv[5];
      #pragma unroll
      for (int f = 0; f < 5; ++f)
        nv[f] = hsum[f*(TH*WSTR) + rh*WSTR + rw];
      #pragma unroll
      for (int f = 0; f < 5; ++f) {
        S[f] += nv[f] - ring[f][8];
        #pragma unroll
        for (int k = 8; k > 0; --k) ring[f][k] = ring[f][k-1];
        ring[f][0] = nv[f];
      }
      if (step >= 8) {  // output slice d = s-4 is in [d_lo, d_lo+DC)
        const float si = S[0], sj = S[1], si2 = S[2], sj2 = S[3], sij = S[4];
        const float cross = sij - si*sj*WIN3_INV;
        const float iv    = si2 - si*si*WIN3_INV;
        const float jv    = sj2 - sj*sj*WIN3_INV;
        acc += cross*cross / (iv*jv + 1e-5f);
      }
    }
    // next iter's staging writes sI/sJ; ordered vs this iter's reads by the
    // syncthreads above (wsum/hsum buffers are distinct from sI/sJ).
  }

  // ---- block reduction -> single atomic ----
  float v = acc;
  #pragma unroll
  for (int off = 32; off > 0; off >>= 1)
    v += __shfl_down(v, off, 64);
  if ((tid & 63) == 0) red[tid >> 6] = v;
  __syncthreads();
  if (tid == 0) {
    const float t = red[0] + red[1] + red[2] + red[3];
    atomicAdd(out, -t / NTOT);
  }
}

extern "C" void kernel_launch(void* const* d_in, const int* in_sizes, int n_in,
                              void* d_out, int out_size, void* d_ws, size_t ws_size,
                              hipStream_t stream) {
  const float* J = (const float*)d_in[0];  // y_pred
  const float* I = (const float*)d_in[1];  // y_true (cc is symmetric in I,J)
  float* out = (float*)d_out;
  hipMemsetAsync(d_out, 0, sizeof(float), stream);
  dim3 grid(W_/TW, H_/TH, B_*NCHUNK);   // 10 x 12 x 16 = 1920 blocks
  ncc_fused<<<grid, dim3(256), 0, stream>>>(I, J, out);
}

// Round 3
// 175.088 us; speedup vs baseline: 1.3065x; 1.3065x over previous
//
#include <hip/hip_runtime.h>

// NCC loss, fully fused, R3: 2-slice macro-steps (3 barriers / 2 slices),
// float4/b128 staging + vectorized w-stage, hoisted addressing, register
// prefetch of next macro's quads, shift-by-2 d-ring, rcp epilogue.
// Vols: [B=2][D=160][H=192][W=160] fp32. Out: scalar -mean(cc).

#define B_    2
#define D_    160
#define H_    192
#define W_    160
#define HW_   (H_*W_)            // 30720
#define TH    16
#define TW    16
#define SH    24
#define SSTR  28                 // stage row stride (%4==0 for b128)
#define SSLC  (SH*SSTR)          // 672 floats per slice per array
#define WSTR  16
#define WFS   (SH*WSTR + 8)      // 392 field stride (pad 8 -> 2-way banks)
#define WSLC  (5*WFS)            // 1960 slice stride
#define HFS   (TH*WSTR + 8)      // 264
#define HSLC  (5*HFS)            // 1320
#define DC    40
#define NMAC  ((DC+8)/2)         // 24 macro steps
#define W3I   (1.0f/729.0f)
#define NTOT  9830400.0f

#define OFF_SJ (2*SSLC)              // 1344
#define OFF_WS (4*SSLC)              // 2688
#define OFF_HS (OFF_WS + 2*WSLC)     // 6608
#define OFF_RED (OFF_HS + 2*HSLC)    // 9248
#define SMEM_TOT (OFF_RED + 8)       // ~37 KB

#if __has_builtin(__builtin_amdgcn_rcpf)
#define RCP(x) __builtin_amdgcn_rcpf(x)
#else
#define RCP(x) (1.0f/(x))
#endif

// sliding 9-window along w: 12 inputs -> 4 outputs, stored as one float4
#define SLIDEX(EXPR, F) { \
  float v_[12]; \
  _Pragma("unroll") for (int k_ = 0; k_ < 12; ++k_) { v_[k_] = (EXPR); } \
  float s_ = v_[0]+v_[1]+v_[2]+v_[3]+v_[4]+v_[5]+v_[6]+v_[7]+v_[8]; \
  float4 o_; o_.x = s_; s_ += v_[9]-v_[0]; o_.y = s_; \
  s_ += v_[10]-v_[1]; o_.z = s_; s_ += v_[11]-v_[2]; o_.w = s_; \
  *(float4*)&sm[wwr + (F)*WFS] = o_; }

__global__ __launch_bounds__(256) void ncc_fused(const float* __restrict__ gI,
                                                 const float* __restrict__ gJ,
                                                 float* __restrict__ out)
{
  __shared__ __align__(16) float sm[SMEM_TOT];
  const int tid  = threadIdx.x;
  const int w0   = blockIdx.x * TW;
  const int h0   = blockIdx.y * TH;
  const int bz   = blockIdx.z;
  const int bb   = bz >> 2;            // 4 chunks per batch
  const int d_lo = (bz & 3) * DC;

  // zero-init stage region (invalid-hw slots stay 0 forever = 'same' pad)
  for (int i = tid; i < OFF_WS; i += 256) sm[i] = 0.f;

  // ---------- staging task precompute (quad = fully in or fully out) ----
  // tasks 0..287: slc = t/144, r = (t%144)/6, c = (t%144)%6
  bool val0 = false, val1 = false;
  int  lds0 = 0, lds1 = 0, slc0 = 0, slc1 = 0;
  const float *pi0 = gI, *pj0 = gJ, *pi1 = gI, *pj1 = gJ;
  {
    const int tA = tid;
    const int tB = (tid >= 224) ? (tid + 32) : 512;  // wave 3 takes 256..287
    auto prep = [&](int t, bool& val, int& lo, int& slc,
                    const float*& pi, const float*& pj) {
      if (t >= 288) { val = false; return; }
      slc = t / 144;
      const int u = t - slc*144;
      const int r = u / 6, c = u - r*6;
      const int gh = h0 - 4 + r;
      const int gw = w0 - 4 + 4*c;
      val = ((unsigned)gh < (unsigned)H_) && (gw >= 0) && (gw + 3 < W_);
      lo  = slc*SSLC + r*SSTR + 4*c;
      const long off = ((long)(bb*D_ + (d_lo - 4 + slc))*H_ + gh)*(long)W_ + gw;
      pi = gI + off; pj = gJ + off;
    };
    prep(tA, val0, lds0, slc0, pi0, pj0);
    prep(tB, val1, lds1, slc1, pi1, pj1);
  }

  // ---------- w-stage precompute: 192 tasks, 4 outputs each ----------
  const bool wact = (tid < 192);
  int wrd = 0, wwr = 0;
  if (wact) {
    const int slc = tid / 96;
    const int u = tid - slc*96;
    const int rr = u >> 2, q = u & 3;
    wrd = slc*SSLC + rr*SSTR + 4*q;
    wwr = OFF_WS + slc*WSLC + rr*WSTR + 4*q;
  }

  // ---------- h-stage precompute: 320 tasks @ 8 outputs ----------
  int h1rd, h1wr, h2rd = 0, h2wr = 0;
  {
    auto prep_h = [&](int t, int& rd, int& wr) {
      const int w = t & 15, rest = t >> 4;
      const int f = rest % 5, g = rest / 5;
      const int half = g & 1, slc = g >> 1;
      rd = OFF_WS + slc*WSLC + f*WFS + (8*half)*WSTR + w;
      wr = OFF_HS + slc*HSLC + f*HFS + (8*half)*WSTR + w;
    };
    prep_h(tid, h1rd, h1wr);
    if (tid >= 192) prep_h(tid + 64, h2rd, h2wr);  // wave 3 takes 256..319
  }
  const bool hact2 = (tid >= 192);

  // ---------- ring precompute ----------
  const int rw = tid & 15, rh = tid >> 4;
  const int hb = OFF_HS + rh*WSTR + rw;

  float ring[5][9], S[5];
  #pragma unroll
  for (int f = 0; f < 5; ++f) {
    S[f] = 0.f;
    #pragma unroll
    for (int k = 0; k < 9; ++k) ring[f][k] = 0.f;
  }
  float acc = 0.f;

  // ---------- prefetch regs + fetch ----------
  float4 f0i = {0,0,0,0}, f0j = {0,0,0,0}, f1i = {0,0,0,0}, f1j = {0,0,0,0};
  auto fetch = [&](int sA) {
    if (val0 && (unsigned)(sA + slc0) < (unsigned)D_) {
      f0i = *(const float4*)pi0; f0j = *(const float4*)pj0;
    } else { f0i = make_float4(0,0,0,0); f0j = make_float4(0,0,0,0); }
    pi0 += 2*HW_; pj0 += 2*HW_;
    if (val1 && (unsigned)(sA + slc1) < (unsigned)D_) {
      f1i = *(const float4*)pi1; f1j = *(const float4*)pj1;
    } else { f1i = make_float4(0,0,0,0); f1j = make_float4(0,0,0,0); }
    pi1 += 2*HW_; pj1 += 2*HW_;
  };

  fetch(d_lo - 4);         // macro 0's slices
  __syncthreads();         // zero-init visible before first stage writes

  int sA = d_lo - 4;
  for (int m = 0; m < NMAC; ++m, sA += 2) {
    // ---- stage: write prefetched quads (zeros for d-OOB slices) ----
    if (val0) { *(float4*)&sm[lds0] = f0i; *(float4*)&sm[lds0 + OFF_SJ] = f0j; }
    if (val1) { *(float4*)&sm[lds1] = f1i; *(float4*)&sm[lds1 + OFF_SJ] = f1j; }
    __syncthreads();                       // B1

    if (m + 1 < NMAC) fetch(sA + 2);       // hide global latency behind compute

    // ---- w-stage: 12 -> 4 sliding, 5 fields, both slices ----
    if (wact) {
      const float4 a0 = *(const float4*)&sm[wrd];
      const float4 a1 = *(const float4*)&sm[wrd + 4];
      const float4 a2 = *(const float4*)&sm[wrd + 8];
      const float4 b0 = *(const float4*)&sm[wrd + OFF_SJ];
      const float4 b1 = *(const float4*)&sm[wrd + OFF_SJ + 4];
      const float4 b2 = *(const float4*)&sm[wrd + OFF_SJ + 8];
      const float wi[12] = {a0.x,a0.y,a0.z,a0.w,a1.x,a1.y,a1.z,a1.w,a2.x,a2.y,a2.z,a2.w};
      const float wj[12] = {b0.x,b0.y,b0.z,b0.w,b1.x,b1.y,b1.z,b1.w,b2.x,b2.y,b2.z,b2.w};
      SLIDEX(wi[k_],          0)
      SLIDEX(wj[k_],          1)
      SLIDEX(wi[k_]*wi[k_],   2)
      SLIDEX(wj[k_]*wj[k_],   3)
      SLIDEX(wi[k_]*wj[k_],   4)
    }
    __syncthreads();                       // B2

    // ---- h-stage: 16 -> 8 sliding ----
    {
      auto hrun = [&](int rd, int wr) {
        float v[16];
        #pragma unroll
        for (int k = 0; k < 16; ++k) v[k] = sm[rd + k*WSTR];
        float s = v[0]+v[1]+v[2]+v[3]+v[4]+v[5]+v[6]+v[7]+v[8];
        sm[wr] = s;
        #pragma unroll
        for (int k = 1; k < 8; ++k) { s += v[k+8] - v[k-1]; sm[wr + k*WSTR] = s; }
      };
      hrun(h1rd, h1wr);
      if (hact2) hrun(h2rd, h2wr);
    }
    __syncthreads();                       // B3

    // ---- d-ring (shift by 2) + cc ----
    {
      float nA[5], nB[5];
      #pragma unroll
      for (int f = 0; f < 5; ++f) {
        nA[f] = sm[hb + f*HFS];
        nB[f] = sm[hb + HSLC + f*HFS];
      }
      float SA[5], SB[5];
      #pragma unroll
      for (int f = 0; f < 5; ++f) {
        SA[f] = S[f] + nA[f] - ring[f][8];
        SB[f] = SA[f] + nB[f] - ring[f][7];
        S[f] = SB[f];
        #pragma unroll
        for (int k = 8; k >= 2; --k) ring[f][k] = ring[f][k-2];
        ring[f][1] = nA[f]; ring[f][0] = nB[f];
      }
      if (m >= 4) {   // outputs d = d_lo-8+2m, +1 within [d_lo, d_lo+DC)
        {
          const float cr = SA[4] - SA[0]*SA[1]*W3I;
          const float vi = SA[2] - SA[0]*SA[0]*W3I;
          const float vj = SA[3] - SA[1]*SA[1]*W3I;
          acc += cr*cr * RCP(vi*vj + 1e-5f);
        }
        {
          const float cr = SB[4] - SB[0]*SB[1]*W3I;
          const float vi = SB[2] - SB[0]*SB[0]*W3I;
          const float vj = SB[3] - SB[1]*SB[1]*W3I;
          acc += cr*cr * RCP(vi*vj + 1e-5f);
        }
      }
    }
    // next macro's stage-writes race-free: w-reads of sI/sJ were before B2,
    // wsum/hsum reads separated by B2/B3.
  }

  // ---- block reduction -> single atomic ----
  float v = acc;
  #pragma unroll
  for (int off = 32; off > 0; off >>= 1)
    v += __shfl_down(v, off, 64);
  if ((tid & 63) == 0) sm[OFF_RED + (tid >> 6)] = v;
  __syncthreads();
  if (tid == 0) {
    const float t = sm[OFF_RED] + sm[OFF_RED+1] + sm[OFF_RED+2] + sm[OFF_RED+3];
    atomicAdd(out, -t / NTOT);
  }
}

extern "C" void kernel_launch(void* const* d_in, const int* in_sizes, int n_in,
                              void* d_out, int out_size, void* d_ws, size_t ws_size,
                              hipStream_t stream) {
  const float* J = (const float*)d_in[0];  // y_pred
  const float* I = (const float*)d_in[1];  // y_true (cc symmetric in I,J)
  float* outp = (float*)d_out;
  hipMemsetAsync(d_out, 0, sizeof(float), stream);
  dim3 grid(W_/TW, H_/TH, B_*4);           // 10 x 12 x 8 = 960 blocks
  ncc_fused<<<grid, dim3(256), 0, stream>>>(I, J, outp);
}

// Round 4
// 172.174 us; speedup vs baseline: 1.3286x; 1.0169x over previous
//
#include <hip/hip_runtime.h>

// NCC loss, fully fused, R4: wave-private column pipeline.
// Each wave owns a 4-wide w-quad; after block-shared raw staging the whole
// w-sum -> h-sum -> d-ring chain is wave-private (no block barriers, just
// lgkmcnt waits). 2 barriers per 2-slice macro. Bank-even strides: raw 28,
// wsum/hsum rows 20, field pads = 4 mod 32. LDS 26.9 KB.
// Vols: [B=2][D=160][H=192][W=160] fp32. Out: scalar -mean(cc).

#define B_    2
#define D_    160
#define H_    192
#define W_    160
#define HW_   (H_*W_)
#define SSTR  28
#define SSLC  (24*SSTR)           // 672
#define OFF_J (2*SSLC)            // 1344: raw J base (after I slc0/slc1)
#define WFS   484                 // wsum field stride (24*20 + 4)
#define OFF_WS 2688
#define HFS   324                 // hsum field stride (16*20 + 4)
#define OFF_HS (OFF_WS + 5*WFS)   // 5108
#define OFF_RED (OFF_HS + 5*HFS)  // 6728
#define SMEM_TOT (OFF_RED + 8)    // 6736 dw = 26.9 KB
#define DC    40
#define NMAC  24                  // (DC+8)/2
#define W3I   (1.0f/729.0f)
#define NTOT  9830400.0f

#if __has_builtin(__builtin_amdgcn_rcpf)
#define RCP(x) __builtin_amdgcn_rcpf(x)
#else
#define RCP(x) (1.0f/(x))
#endif

#define LGKM0() asm volatile("s_waitcnt lgkmcnt(0)" ::: "memory")

// sliding 9-window along w: 12 inputs -> 4 outputs as one float4
#define SLIDEX(EXPR, F) { \
  float v_[12]; \
  _Pragma("unroll") for (int k_ = 0; k_ < 12; ++k_) { v_[k_] = (EXPR); } \
  float s_ = v_[0]+v_[1]+v_[2]+v_[3]+v_[4]+v_[5]+v_[6]+v_[7]+v_[8]; \
  float4 o_; o_.x = s_; s_ += v_[9]-v_[0]; o_.y = s_; \
  s_ += v_[10]-v_[1]; o_.z = s_; s_ += v_[11]-v_[2]; o_.w = s_; \
  *(float4*)&sm[wwr + (F)*WFS] = o_; }

__global__ __launch_bounds__(256, 4) void ncc_fused(const float* __restrict__ gI,
                                                    const float* __restrict__ gJ,
                                                    float* __restrict__ out)
{
  __shared__ __align__(16) float sm[SMEM_TOT];
  const int tid  = threadIdx.x;
  const int lane = tid & 63;
  const int Q    = tid >> 6;           // wave id = w-quad owner
  const int w0   = blockIdx.x * 16;
  const int h0   = blockIdx.y * 16;
  const int bz   = blockIdx.z;
  const int bb   = bz >> 2;
  const int d_lo = (bz & 3) * DC;

  // zero raw region once; invalid-hw slots stay 0 = 'same' zero pad
  for (int i = tid; i < OFF_WS; i += 256) sm[i] = 0.f;

  // ---------- staging task precompute: 288 tasks = 2 slc x 24 r x 6 quads ----
  bool val0 = false, val1 = false;
  int  lds0 = 0, lds1 = 0, slc0 = 0, slc1 = 0;
  const float *pi0 = gI, *pj0 = gJ, *pi1 = gI, *pj1 = gJ;
  {
    const int tA = tid;
    const int tB = (tid >= 224) ? (tid + 32) : 512;  // wave 3 takes 256..287
    auto prep = [&](int t, bool& val, int& lo, int& slc,
                    const float*& pi, const float*& pj) {
      if (t >= 288) { val = false; return; }
      slc = t / 144;
      const int u = t - slc*144;
      const int r = u / 6, c = u - r*6;
      const int gh = h0 - 4 + r;
      const int gw = w0 - 4 + 4*c;
      val = ((unsigned)gh < (unsigned)H_) && (gw >= 0) && (gw + 3 < W_);
      lo  = slc*SSLC + r*SSTR + 4*c;
      const long off = ((long)(bb*D_ + (d_lo - 4 + slc))*H_ + gh)*(long)W_ + gw;
      pi = gI + off; pj = gJ + off;
    };
    prep(tA, val0, lds0, slc0, pi0, pj0);
    prep(tB, val1, lds1, slc1, pi1, pj1);
  }

  // ---------- w-stage: lane = row (0..23), quad = Q ----------
  const bool wact = (lane < 24);
  const int  wrd  = lane*SSTR + 4*Q;          // + slc*SSLC ; +OFF_J for J
  const int  wwr  = OFF_WS + lane*20 + 4*Q;   // + f*WFS

  // ---------- h-stage: 40 tasks = 4 wq x 5 f x 2 half ----------
  const bool hact  = (lane < 40);
  const int  hwq   = lane & 3;
  const int  hf    = (lane >> 2) % 5;
  const int  hhalf = lane / 20;
  const int  hrd   = OFF_WS + hf*WFS + hhalf*160 + 4*Q + hwq;  // + k*20
  const int  hwr   = OFF_HS + hf*HFS + hhalf*160 + 4*Q + hwq;  // + j*20

  // ---------- ring: lane -> (rh = lane>>2, wq = lane&3) ----------
  const int rh = lane >> 2, rwq = lane & 3;
  const int hb = OFF_HS + rh*20 + 4*Q + rwq;  // + f*HFS

  float ring[5][9], S[5];
  #pragma unroll
  for (int f = 0; f < 5; ++f) {
    S[f] = 0.f;
    #pragma unroll
    for (int k = 0; k < 9; ++k) ring[f][k] = 0.f;
  }
  float acc = 0.f;

  // ---------- global prefetch regs ----------
  float4 f0i = {0,0,0,0}, f0j = {0,0,0,0}, f1i = {0,0,0,0}, f1j = {0,0,0,0};
  auto fetch = [&](int sbase) {
    if (val0 && (unsigned)(sbase + slc0) < (unsigned)D_) {
      f0i = *(const float4*)pi0; f0j = *(const float4*)pj0;
    } else { f0i = make_float4(0,0,0,0); f0j = make_float4(0,0,0,0); }
    pi0 += 2*HW_; pj0 += 2*HW_;
    if (val1 && (unsigned)(sbase + slc1) < (unsigned)D_) {
      f1i = *(const float4*)pi1; f1j = *(const float4*)pj1;
    } else { f1i = make_float4(0,0,0,0); f1j = make_float4(0,0,0,0); }
    pi1 += 2*HW_; pj1 += 2*HW_;
  };

  fetch(d_lo - 4);
  __syncthreads();   // zero-init visible
  if (val0) { *(float4*)&sm[lds0] = f0i; *(float4*)&sm[lds0 + OFF_J] = f0j; }
  if (val1) { *(float4*)&sm[lds1] = f1i; *(float4*)&sm[lds1 + OFF_J] = f1j; }
  __syncthreads();   // B2: macro 0's raw ready

  int sA = d_lo - 4;
  for (int m = 0; m < NMAC; ++m, sA += 2) {
    if (m + 1 < NMAC) fetch(sA + 2);   // hide global latency behind the chain

    #pragma unroll
    for (int slc = 0; slc < 2; ++slc) {
      // ---- w-stage (wave-private columns) ----
      if (wact) {
        const int rb = wrd + slc*SSLC;
        const float4 a0 = *(const float4*)&sm[rb];
        const float4 a1 = *(const float4*)&sm[rb + 4];
        const float4 a2 = *(const float4*)&sm[rb + 8];
        const float4 b0 = *(const float4*)&sm[rb + OFF_J];
        const float4 b1 = *(const float4*)&sm[rb + OFF_J + 4];
        const float4 b2 = *(const float4*)&sm[rb + OFF_J + 8];
        const float wi[12] = {a0.x,a0.y,a0.z,a0.w,a1.x,a1.y,a1.z,a1.w,a2.x,a2.y,a2.z,a2.w};
        const float wj[12] = {b0.x,b0.y,b0.z,b0.w,b1.x,b1.y,b1.z,b1.w,b2.x,b2.y,b2.z,b2.w};
        SLIDEX(wi[k_],        0)
        SLIDEX(wj[k_],        1)
        SLIDEX(wi[k_]*wi[k_], 2)
        SLIDEX(wj[k_]*wj[k_], 3)
        SLIDEX(wi[k_]*wj[k_], 4)
      }
      LGKM0();   // wsum visible to own wave

      // ---- h-stage (wave-private) ----
      if (hact) {
        float v[16];
        #pragma unroll
        for (int k = 0; k < 16; ++k) v[k] = sm[hrd + k*20];
        float s = v[0]+v[1]+v[2]+v[3]+v[4]+v[5]+v[6]+v[7]+v[8];
        sm[hwr] = s;
        #pragma unroll
        for (int j = 1; j < 8; ++j) { s += v[j+8] - v[j-1]; sm[hwr + j*20] = s; }
      }
      LGKM0();   // hsum visible to own wave

      // ---- d-ring + cc (all 256 lanes: output (rh, 4Q+rwq)) ----
      {
        float nv[5];
        #pragma unroll
        for (int f = 0; f < 5; ++f) nv[f] = sm[hb + f*HFS];
        #pragma unroll
        for (int f = 0; f < 5; ++f) {
          S[f] += nv[f] - ring[f][8];
          #pragma unroll
          for (int k = 8; k > 0; --k) ring[f][k] = ring[f][k-1];
          ring[f][0] = nv[f];
        }
        if (m >= 4) {
          const float cr = S[4] - S[0]*S[1]*W3I;
          const float vi = S[2] - S[0]*S[0]*W3I;
          const float vj = S[3] - S[1]*S[1]*W3I;
          acc += cr*cr * RCP(vi*vj + 1e-5f);
        }
      }
      LGKM0();   // ring/h reads drained before next slice's wsum overwrite
    }

    __syncthreads();                   // B1: all raw reads of macro m done
    if (m + 1 < NMAC) {
      if (val0) { *(float4*)&sm[lds0] = f0i; *(float4*)&sm[lds0 + OFF_J] = f0j; }
      if (val1) { *(float4*)&sm[lds1] = f1i; *(float4*)&sm[lds1 + OFF_J] = f1j; }
    }
    __syncthreads();                   // B2: macro m+1's raw ready
  }

  // ---- block reduction -> single atomic ----
  float v = acc;
  #pragma unroll
  for (int off = 32; off > 0; off >>= 1)
    v += __shfl_down(v, off, 64);
  if (lane == 0) sm[OFF_RED + Q] = v;
  __syncthreads();
  if (tid == 0) {
    const float t = sm[OFF_RED] + sm[OFF_RED+1] + sm[OFF_RED+2] + sm[OFF_RED+3];
    atomicAdd(out, -t / NTOT);
  }
}

extern "C" void kernel_launch(void* const* d_in, const int* in_sizes, int n_in,
                              void* d_out, int out_size, void* d_ws, size_t ws_size,
                              hipStream_t stream) {
  const float* J = (const float*)d_in[0];  // y_pred
  const float* I = (const float*)d_in[1];  // y_true (cc symmetric in I,J)
  float* outp = (float*)d_out;
  hipMemsetAsync(d_out, 0, sizeof(float), stream);
  dim3 grid(W_/16, H_/16, B_*4);           // 10 x 12 x 8 = 960 blocks
  ncc_fused<<<grid, dim3(256), 0, stream>>>(I, J, outp);
}